// Round 3
// baseline (539.194 us; speedup 1.0000x reference)
//
#include <hip/hip_runtime.h>

// N=51200 nodes, E=800000 edges (E%16==0), G=128, DIN=DE=DOUT=64, DG=128
//   AB[i][0:64]   = h_node[i] @ W1[0:64,:] + b1      (A', bias folded)
//   AB[i][64:128] = h_node[i] @ W1[64:128,:]         (B)      [bf16]
//   msg_e  = relu(relu(A'[src]+B[dst]+h_edge@W1c) @ W2 + b2)
//   gg[g]  = sum_{e: graph(dst_e)=g} msg_e                    [G,64] f32
//   out[g] = relu(concat(u[g], gg[g]@Wn + cnt_g*bn) @ Wg + bg)
// MFMA 16x16x32 bf16, feats = M rows, edges/nodes = N cols.
//   C/D: col=lane&15, row=quad*4+reg ; A/B frag: [free=lane&15][k=quad*8+j]

typedef __attribute__((ext_vector_type(8))) short short8;
typedef __attribute__((ext_vector_type(4))) float f32x4;

#define WB() __builtin_amdgcn_wave_barrier()
#define IMIN(a,b) ((a)<(b)?(a):(b))

__device__ inline unsigned short f2bfu(float x) {
    unsigned u = __builtin_bit_cast(unsigned, x);
    u += 0x7fffu + ((u >> 16) & 1u);
    return (unsigned short)(u >> 16);
}
__device__ inline short f2bf(float x) { return (short)f2bfu(x); }
__device__ inline unsigned pack2(float a, float b) {
    return (unsigned)f2bfu(a) | ((unsigned)f2bfu(b) << 16);
}
__device__ inline short8 cvt8(f32x4 a, f32x4 b) {
    short8 r;
    r[0]=f2bf(a[0]); r[1]=f2bf(a[1]); r[2]=f2bf(a[2]); r[3]=f2bf(a[3]);
    r[4]=f2bf(b[0]); r[5]=f2bf(b[1]); r[6]=f2bf(b[2]); r[7]=f2bf(b[3]);
    return r;
}
__device__ inline f32x4 bf4f(uint2 p) {       // 4 packed bf16 -> f32x4
    f32x4 r;
    r[0] = __builtin_bit_cast(float, p.x << 16);
    r[1] = __builtin_bit_cast(float, p.x & 0xffff0000u);
    r[2] = __builtin_bit_cast(float, p.y << 16);
    r[3] = __builtin_bit_cast(float, p.y & 0xffff0000u);
    return r;
}

// ---------------------------------------------------------------------------
// K0: AB (bf16) via MFMA; b1 folded into the A half.
__global__ __launch_bounds__(256) void k_node_mfma(
    const float* __restrict__ h_node, const float* __restrict__ W1,
    const float* __restrict__ b1, unsigned short* __restrict__ AB, int N)
{
    const int lane = threadIdx.x & 63;
    const int quad = lane >> 4, col = lane & 15;

    short8 wf[2][8];
    for (int ks = 0; ks < 2; ++ks)
        for (int mt = 0; mt < 8; ++mt) {
            const int feat = mt * 16 + col;
            const float* Wc = W1 + (size_t)((feat >> 6) * 64) * 64 + (feat & 63);
            short8 f;
            for (int j = 0; j < 8; ++j) f[j] = f2bf(Wc[(size_t)(ks * 32 + quad * 8 + j) * 64]);
            wf[ks][mt] = f;
        }
    f32x4 binit[8];
    for (int mt = 0; mt < 8; ++mt) {
        if (mt < 4) binit[mt] = *(const f32x4*)(b1 + mt * 16 + quad * 4);
        else        binit[mt] = (f32x4){0.f, 0.f, 0.f, 0.f};
    }

    const int wid = (blockIdx.x * blockDim.x + threadIdx.x) >> 6;
    const int nw  = (gridDim.x * blockDim.x) >> 6;
    const int ntiles = N >> 4;
    for (int t = wid; t < ntiles; t += nw) {
        const int node = t * 16 + col;
        const float* xr = h_node + (size_t)node * 64 + quad * 8;
        f32x4 x0 = *(const f32x4*)(xr);
        f32x4 x1 = *(const f32x4*)(xr + 4);
        f32x4 x2 = *(const f32x4*)(xr + 32);
        f32x4 x3 = *(const f32x4*)(xr + 36);
        short8 xb0 = cvt8(x0, x1), xb1 = cvt8(x2, x3);

        f32x4 acc[8];
#pragma unroll
        for (int mt = 0; mt < 8; ++mt) acc[mt] = binit[mt];
#pragma unroll
        for (int mt = 0; mt < 8; ++mt)
            acc[mt] = __builtin_amdgcn_mfma_f32_16x16x32_bf16(wf[0][mt], xb0, acc[mt], 0, 0, 0);
#pragma unroll
        for (int mt = 0; mt < 8; ++mt)
            acc[mt] = __builtin_amdgcn_mfma_f32_16x16x32_bf16(wf[1][mt], xb1, acc[mt], 0, 0, 0);

        unsigned short* orow = AB + (size_t)node * 128 + quad * 4;
#pragma unroll
        for (int mt = 0; mt < 8; ++mt) {
            uint2 p;
            p.x = pack2(acc[mt][0], acc[mt][1]);
            p.y = pack2(acc[mt][2], acc[mt][3]);
            *(uint2*)(orow + mt * 16) = p;
        }
    }
}

// ---------------------------------------------------------------------------
// K1: fused edge MLP + per-graph scatter, software-pipelined.
__global__ __launch_bounds__(256) void k_edge_mfma(
    const float* __restrict__ h_edge, const unsigned short* __restrict__ AB,
    const float* __restrict__ W1, const float* __restrict__ W2,
    const float* __restrict__ b2,
    const int* __restrict__ src, const int* __restrict__ dst,
    const int* __restrict__ ngid,
    float* __restrict__ gg, int E)
{
    __shared__ float sgg[128 * 65];        // 33.3 KB per-graph accumulator
    __shared__ short tlds[4][16 * 72];     // per-wave layer1->layer2 tile
    const int wave = threadIdx.x >> 6, lane = threadIdx.x & 63;
    const int quad = lane >> 4, col = lane & 15;

    for (int i = threadIdx.x; i < 128 * 65; i += 256) sgg[i] = 0.f;

    short8 w1f[2][4], w2f[2][4];
    for (int ks = 0; ks < 2; ++ks)
        for (int mt = 0; mt < 4; ++mt) {
            const int feat = mt * 16 + col;
            short8 f1, f2;
            for (int j = 0; j < 8; ++j) {
                const int k = ks * 32 + quad * 8 + j;
                f1[j] = f2bf(W1[(size_t)(128 + k) * 64 + feat]);
                f2[j] = f2bf(W2[(size_t)k * 64 + feat]);
            }
            w1f[ks][mt] = f1; w2f[ks][mt] = f2;
        }
    f32x4 bb2[4];
#pragma unroll
    for (int mt = 0; mt < 4; ++mt) bb2[mt] = *(const f32x4*)(b2 + mt * 16 + quad * 4);
    __syncthreads();

    short* tl = tlds[wave];
    const int wid = (blockIdx.x * blockDim.x + threadIdx.x) >> 6;
    const int nwv = (gridDim.x * blockDim.x) >> 6;
    const int ntiles = E >> 4;
    const int per = (ntiles + nwv - 1) / nwv;
    const int t0 = wid * per;
    const int t1 = IMIN(t0 + per, ntiles);

#define LOADI(tt, sx, dx) { const int ee = (tt) * 16 + col; sx = src[ee]; dx = dst[ee]; }
#define LOADD(sx, dx, tt, gv, ap, bp, xv) { \
    gv = ngid[dx]; \
    const unsigned short* a_ = AB + (size_t)(sx) * 128 + quad * 4; \
    const unsigned short* c_ = AB + (size_t)(dx) * 128 + 64 + quad * 4; \
    ap[0] = *(const uint2*)(a_);      ap[1] = *(const uint2*)(a_ + 16); \
    ap[2] = *(const uint2*)(a_ + 32); ap[3] = *(const uint2*)(a_ + 48); \
    bp[0] = *(const uint2*)(c_);      bp[1] = *(const uint2*)(c_ + 16); \
    bp[2] = *(const uint2*)(c_ + 32); bp[3] = *(const uint2*)(c_ + 48); \
    const float* x_ = h_edge + (size_t)((tt) * 16 + col) * 64 + quad * 8; \
    xv[0] = *(const f32x4*)(x_);      xv[1] = *(const f32x4*)(x_ + 4); \
    xv[2] = *(const f32x4*)(x_ + 32); xv[3] = *(const f32x4*)(x_ + 36); }

#define COMPUTE(gv, ap, bp, xv) { \
    short8 xb0 = cvt8(xv[0], xv[1]), xb1 = cvt8(xv[2], xv[3]); \
    f32x4 acc[4]; \
    _Pragma("unroll") \
    for (int mt = 0; mt < 4; ++mt) acc[mt] = bf4f(ap[mt]) + bf4f(bp[mt]); \
    _Pragma("unroll") \
    for (int mt = 0; mt < 4; ++mt) \
        acc[mt] = __builtin_amdgcn_mfma_f32_16x16x32_bf16(w1f[0][mt], xb0, acc[mt], 0, 0, 0); \
    _Pragma("unroll") \
    for (int mt = 0; mt < 4; ++mt) \
        acc[mt] = __builtin_amdgcn_mfma_f32_16x16x32_bf16(w1f[1][mt], xb1, acc[mt], 0, 0, 0); \
    _Pragma("unroll") \
    for (int mt = 0; mt < 4; ++mt) { \
        uint2 p; \
        p.x = pack2(fmaxf(acc[mt][0], 0.f), fmaxf(acc[mt][1], 0.f)); \
        p.y = pack2(fmaxf(acc[mt][2], 0.f), fmaxf(acc[mt][3], 0.f)); \
        *(uint2*)&tl[col * 72 + mt * 16 + quad * 4] = p; \
    } \
    WB(); \
    short8 tb0 = *(const short8*)&tl[col * 72 + quad * 8]; \
    short8 tb1 = *(const short8*)&tl[col * 72 + 32 + quad * 8]; \
    f32x4 ac2[4]; \
    _Pragma("unroll") \
    for (int mt = 0; mt < 4; ++mt) ac2[mt] = bb2[mt]; \
    _Pragma("unroll") \
    for (int mt = 0; mt < 4; ++mt) \
        ac2[mt] = __builtin_amdgcn_mfma_f32_16x16x32_bf16(w2f[0][mt], tb0, ac2[mt], 0, 0, 0); \
    _Pragma("unroll") \
    for (int mt = 0; mt < 4; ++mt) \
        ac2[mt] = __builtin_amdgcn_mfma_f32_16x16x32_bf16(w2f[1][mt], tb1, ac2[mt], 0, 0, 0); \
    WB(); \
    float* sg_ = sgg + gv * 65; \
    _Pragma("unroll") \
    for (int mt = 0; mt < 4; ++mt) { \
        _Pragma("unroll") \
        for (int r = 0; r < 4; ++r) \
            atomicAdd(&sg_[mt * 16 + quad * 4 + r], fmaxf(ac2[mt][r], 0.f)); \
    } }

    if (t0 < t1) {
        int s0i, d0i, s1i, d1i, g0, g1;
        uint2 a0[4], b0[4], a1[4], b1p[4];
        f32x4 x0[4], x1[4];
        LOADI(t0, s0i, d0i);
        LOADI(IMIN(t0 + 1, t1 - 1), s1i, d1i);
        LOADD(s0i, d0i, t0, g0, a0, b0, x0);
        LOADI(IMIN(t0 + 2, t1 - 1), s0i, d0i);
        LOADD(s1i, d1i, IMIN(t0 + 1, t1 - 1), g1, a1, b1p, x1);
        LOADI(IMIN(t0 + 3, t1 - 1), s1i, d1i);
        for (int t = t0; t < t1; t += 2) {
            COMPUTE(g0, a0, b0, x0);                       // tile t
            LOADD(s0i, d0i, IMIN(t + 2, t1 - 1), g0, a0, b0, x0);
            LOADI(IMIN(t + 4, t1 - 1), s0i, d0i);
            if (t + 1 < t1) {
                COMPUTE(g1, a1, b1p, x1);                  // tile t+1
                LOADD(s1i, d1i, IMIN(t + 3, t1 - 1), g1, a1, b1p, x1);
                LOADI(IMIN(t + 5, t1 - 1), s1i, d1i);
            }
        }
    }
    __syncthreads();

    // HW fp32 atomics (global_atomic_add_f32) — NOT the CAS loop plain
    // atomicAdd(float*) lowers to without -munsafe-fp-atomics.
    for (int i = threadIdx.x; i < 128 * 64; i += 256)
        unsafeAtomicAdd(&gg[i], sgg[(i >> 6) * 65 + (i & 63)]);
#undef LOADI
#undef LOADD
#undef COMPUTE
}

// ---------------------------------------------------------------------------
// K2: per-graph epilogue; cnt via binary search on sorted node_graph_id.
__global__ __launch_bounds__(128) void k_final(
    const float* __restrict__ u, const float* __restrict__ gg,
    const int* __restrict__ ngid, int N,
    const float* __restrict__ Wn, const float* __restrict__ bn,
    const float* __restrict__ Wg, const float* __restrict__ bg,
    float* __restrict__ out)
{
    const int g = blockIdx.x, t = threadIdx.x;
    __shared__ float sgg[64];
    __shared__ float sn[64];
    __shared__ int scnt;
    if (t == 0) {
        int lo = 0, hi = N;
        while (lo < hi) { int m = (lo + hi) >> 1; if (ngid[m] < g) lo = m + 1; else hi = m; }
        const int a = lo;
        lo = 0; hi = N;
        while (lo < hi) { int m = (lo + hi) >> 1; if (ngid[m] < g + 1) lo = m + 1; else hi = m; }
        scnt = lo - a;
    }
    if (t < 64) sgg[t] = gg[g * 64 + t];
    __syncthreads();
    if (t < 64) {
        float acc = bn[t] * (float)scnt;
        for (int k = 0; k < 64; ++k)
            acc = fmaf(sgg[k], Wn[k * 64 + t], acc);
        sn[t] = acc;
    }
    __syncthreads();
    float acc = bg[t];
    for (int k = 0; k < 128; ++k)
        acc = fmaf(u[g * 128 + k], Wg[k * 128 + t], acc);
    for (int k = 0; k < 64; ++k)
        acc = fmaf(sn[k], Wg[(128 + k) * 128 + t], acc);
    out[g * 128 + t] = fmaxf(acc, 0.f);
}

// ---------------------------------------------------------------------------
extern "C" void kernel_launch(void* const* d_in, const int* in_sizes, int n_in,
                              void* d_out, int out_size, void* d_ws, size_t ws_size,
                              hipStream_t stream)
{
    const float* h_node = (const float*)d_in[0];
    const float* h_edge = (const float*)d_in[1];
    const float* u      = (const float*)d_in[2];
    const float* W1     = (const float*)d_in[3];
    const float* b1     = (const float*)d_in[4];
    const float* W2     = (const float*)d_in[5];
    const float* b2     = (const float*)d_in[6];
    const float* Wn     = (const float*)d_in[7];
    const float* bn     = (const float*)d_in[8];
    const float* Wg     = (const float*)d_in[9];
    const float* bg     = (const float*)d_in[10];
    const int*   src    = (const int*)d_in[11];
    const int*   dst    = (const int*)d_in[12];
    const int*   ngid   = (const int*)d_in[13];

    const int N = in_sizes[0] / 64;
    const int E = in_sizes[1] / 64;
    const int G = in_sizes[2] / 128;

    unsigned short* AB = (unsigned short*)d_ws;            // N*128 bf16 (13.1 MB)
    float* gg = (float*)(AB + (size_t)N * 128);            // G*64 f32

    hipMemsetAsync(gg, 0, (size_t)G * 64 * sizeof(float), stream);

    k_node_mfma<<<400, 256, 0, stream>>>(h_node, W1, b1, AB, N);
    k_edge_mfma<<<768, 256, 0, stream>>>(h_edge, AB, W1, W2, b2, src, dst, ngid, gg, E);
    k_final<<<G, 128, 0, stream>>>(u, gg, ngid, N, Wn, bn, Wg, bg, (float*)d_out);
}